// Round 1
// 845.098 us; speedup vs baseline: 1.0989x; 1.0989x over previous
//
#include <hip/hip_runtime.h>
#include <stdint.h>

// Problem constants: only layers 4 and 11 survive the skip set.
#define Lc   12
#define Bc   32
#define Hc   12
#define Nc   197
#define NNc  (Nc * Nc)      // 38809
#define NG4  9703           // ceil(38809/4) float4 groups per slice
#define STRIDEc 38812       // slice stride padded to multiple of 4 (16B alignment)
#define Kc   9702           // int(38809 * 0.25)
#define NLB  64             // 2 layers * 32 batches

#define HBINS 2048
#define CAP   2048
#define PADV  2.0f          // pad value: strictly greater than any mean (< 1.0)

// ---------------------------------------------------------------------------
// Kernel 1: head-mean. 4 elements per thread, float4 store into padded buffer.
// Per-element h-summation order identical to reference-passing version.
// ---------------------------------------------------------------------------
__global__ void __launch_bounds__(256) head_mean_kernel(const float* __restrict__ in,
                                                        float* __restrict__ mean) {
    int j4 = blockIdx.x * 256 + threadIdx.x;   // float4-group index
    int lb = blockIdx.y;                       // 0..63 : lsel*32 + b
    if (j4 >= NG4) return;
    int b     = lb & 31;
    int layer = (lb >> 5) ? 11 : 4;
    int j = j4 * 4;
    const float* base = in + ((size_t)(layer * Bc + b)) * Hc * NNc + j;
    float* mp = mean + (size_t)lb * STRIDEc;

    if (j + 4 <= NNc) {
        float a0 = 0.f, a1 = 0.f, a2 = 0.f, a3 = 0.f;
        #pragma unroll
        for (int h = 0; h < Hc; ++h) {
            const float* p = base + (size_t)h * NNc;
            a0 += p[0]; a1 += p[1]; a2 += p[2]; a3 += p[3];
        }
        float4 r;
        r.x = a0 / 12.0f; r.y = a1 / 12.0f; r.z = a2 / 12.0f; r.w = a3 / 12.0f;
        *reinterpret_cast<float4*>(mp + j) = r;
    } else {
        // tail group: element 38808 is real, 38809..38811 are pads
        for (int e = j; e < STRIDEc; ++e) {
            if (e < NNc) {
                float a = 0.f;
                #pragma unroll
                for (int h = 0; h < Hc; ++h) a += base[(size_t)h * NNc + (e - j)];
                mp[e] = a / 12.0f;
            } else {
                mp[e] = PADV;
            }
        }
    }
}

// ---------------------------------------------------------------------------
// Kernel 2: fused radix-select (exact Kc-th smallest + stable tie cutoff)
// and row-normalize. One 1024-thread block per lb.
// Radix passes 11/11/10 bits over float bit patterns (values in [0,1)).
// Pads (2.0f) land in strictly higher bins -> never affect the selection.
// ---------------------------------------------------------------------------
__global__ void __launch_bounds__(1024) select_norm_kernel(float* __restrict__ mean) {
    const int lb   = blockIdx.x;
    const int tid  = threadIdx.x;
    const int lane = tid & 63;
    const int wid  = tid >> 6;          // 16 waves
    float* vbuf = mean + (size_t)lb * STRIDEc;
    const float4* v4 = reinterpret_cast<const float4*>(vbuf);

    __shared__ int hist[HBINS];
    __shared__ int wtot[16];
    __shared__ int s_bin, s_cum, s_cnt, s_cut;
    __shared__ int list[CAP];

    int kreq = Kc;
    unsigned prefix = 0;

    #pragma unroll
    for (int pass = 0; pass < 3; ++pass) {
        const int shift  = (pass == 0) ? 21 : (pass == 1) ? 10 : 0;
        const int mask   = (pass == 2) ? 0x3FF : 0x7FF;
        const int pshift = (pass == 1) ? 21 : 10;   // prefix-check shift (pass>=1)

        for (int i = tid; i < HBINS; i += 1024) hist[i] = 0;
        __syncthreads();

        for (int i = tid; i < NG4; i += 1024) {
            float4 vv = v4[i];
            float vals[4] = {vv.x, vv.y, vv.z, vv.w};
            #pragma unroll
            for (int c = 0; c < 4; ++c) {
                unsigned bits = __float_as_uint(vals[c]);
                bool ok = (pass == 0) || ((bits >> pshift) == prefix);
                if (ok) atomicAdd(&hist[(bits >> shift) & mask], 1);
            }
        }
        __syncthreads();

        // parallel exclusive scan over 2048 bins, 2 bins per thread
        int h0 = hist[2 * tid];
        int h1 = hist[2 * tid + 1];
        int pairSum = h0 + h1;
        int incl = pairSum;
        #pragma unroll
        for (int off = 1; off < 64; off <<= 1) {
            int t = __shfl_up(incl, off, 64);
            if (lane >= off) incl += t;
        }
        if (lane == 63) wtot[wid] = incl;
        __syncthreads();
        int woff = 0;
        #pragma unroll
        for (int w = 0; w < 16; ++w) woff += (w < wid) ? wtot[w] : 0;
        int excl = woff + incl - pairSum;

        int c0 = excl, c1 = excl + h0;
        if (c0 < kreq && c0 + h0 >= kreq) { s_bin = 2 * tid;     s_cum = c0; }
        if (c1 < kreq && c1 + h1 >= kreq) { s_bin = 2 * tid + 1; s_cum = c1; }
        __syncthreads();

        kreq -= s_cum;
        if (pass == 0)      prefix = (unsigned)s_bin;
        else if (pass == 1) prefix = (prefix << 11) | (unsigned)s_bin;
        else                prefix = (prefix << 10) | (unsigned)s_bin;
        __syncthreads();
    }

    // prefix == exact bits of the Kc-th smallest; kreq == #equal values to zero
    if (tid == 0) s_cnt = 0;
    __syncthreads();
    for (int i = tid; i < NG4; i += 1024) {
        float4 vv = v4[i];
        float vals[4] = {vv.x, vv.y, vv.z, vv.w};
        #pragma unroll
        for (int c = 0; c < 4; ++c) {
            if (__float_as_uint(vals[c]) == prefix) {
                int p = atomicAdd(&s_cnt, 1);
                if (p < CAP) list[p] = i * 4 + c;
            }
        }
    }
    __syncthreads();
    if (tid == 0) {
        int m = s_cnt < CAP ? s_cnt : CAP;
        int t = kreq;            // in [1, m]
        int last = -1;
        for (int s2 = 0; s2 < t && s2 < m; ++s2) {   // t-th smallest index; t tiny
            int mn = 0x7FFFFFFF;
            for (int q = 0; q < m; ++q) { int x = list[q]; if (x > last && x < mn) mn = x; }
            last = mn;
        }
        s_cut = last;
    }
    __syncthreads();

    const float thr = __uint_as_float(prefix);
    const int   cut = s_cut;

    // ---- fused norm: zero selected (exempt idx 0), (x+I)*0.5, row-normalize ----
    for (int r = wid; r < Nc; r += 16) {
        float a[4];
        float sum = 0.f;
        #pragma unroll
        for (int q = 0; q < 4; ++q) {
            int c = lane + q * 64;
            float av = 0.f;
            if (c < Nc) {
                int idx  = r * Nc + c;
                float vv = vbuf[idx];
                bool zero = (idx != 0) && (vv < thr || (vv == thr && idx <= cut));
                float x = zero ? 0.f : vv;
                av = (x + (r == c ? 1.0f : 0.0f)) * 0.5f;
            }
            a[q] = av;
            sum += av;
        }
        #pragma unroll
        for (int off = 32; off > 0; off >>= 1) sum += __shfl_xor(sum, off, 64);
        #pragma unroll
        for (int q = 0; q < 4; ++q) {
            int c = lane + q * 64;
            if (c < Nc) vbuf[r * Nc + c] = a[q] / sum;
        }
    }
}

// ---------------------------------------------------------------------------
// Kernel 3: batched fp32 matmul  C[b] = A11n[b] @ A4n[b], 197x197.
// 32x32 tiles, 2x2 per thread (1.0 FMA per ds_read, half the global traffic).
// k-accumulation order ascending -> bitwise identical to prior passing version.
// ---------------------------------------------------------------------------
__global__ void __launch_bounds__(256) matmul_kernel(const float* __restrict__ buf,
                                                     float* __restrict__ C) {
    int b = blockIdx.z;
    const float* A  = buf + (size_t)(32 + b) * STRIDEc;   // layer 11 normalized
    const float* Bm = buf + (size_t)b * STRIDEc;          // layer 4 normalized
    float* Cb = C + (size_t)b * NNc;

    __shared__ float As[32][33];
    __shared__ float Bs[32][33];
    int tid = threadIdx.x;
    int tx = tid & 15, ty = tid >> 4;
    int i0 = blockIdx.y * 32, j0 = blockIdx.x * 32;
    float acc00 = 0.f, acc01 = 0.f, acc10 = 0.f, acc11 = 0.f;

    for (int k0 = 0; k0 < Nc; k0 += 32) {
        #pragma unroll
        for (int q = 0; q < 4; ++q) {
            int e = tid + q * 256;
            int r = e >> 5, c2 = e & 31;
            int ar = i0 + r, ac = k0 + c2;
            As[r][c2] = (ar < Nc && ac < Nc) ? A[ar * Nc + ac] : 0.f;
            int br = k0 + r, bc = j0 + c2;
            Bs[r][c2] = (br < Nc && bc < Nc) ? Bm[br * Nc + bc] : 0.f;
        }
        __syncthreads();
        #pragma unroll
        for (int kk = 0; kk < 32; ++kk) {
            float a0 = As[ty][kk],      a1 = As[ty + 16][kk];
            float b0 = Bs[kk][tx],      b1 = Bs[kk][tx + 16];
            acc00 += a0 * b0; acc01 += a0 * b1;
            acc10 += a1 * b0; acc11 += a1 * b1;
        }
        __syncthreads();
    }

    int i = i0 + ty, j = j0 + tx;
    if (i < Nc) {
        if (j < Nc)      Cb[i * Nc + j]        = acc00;
        if (j + 16 < Nc) Cb[i * Nc + j + 16]   = acc01;
    }
    if (i + 16 < Nc) {
        if (j < Nc)      Cb[(i + 16) * Nc + j]      = acc10;
        if (j + 16 < Nc) Cb[(i + 16) * Nc + j + 16] = acc11;
    }
}

// ---------------------------------------------------------------------------
extern "C" void kernel_launch(void* const* d_in, const int* in_sizes, int n_in,
                              void* d_out, int out_size, void* d_ws, size_t ws_size,
                              hipStream_t stream) {
    const float* attn = (const float*)d_in[0];
    float* out = (float*)d_out;

    // workspace: 64 padded slices of 38812 floats (~9.94 MB)
    float* buf = (float*)d_ws;

    dim3 g1((NG4 + 255) / 256, NLB);
    head_mean_kernel<<<g1, 256, 0, stream>>>(attn, buf);

    select_norm_kernel<<<NLB, 1024, 0, stream>>>(buf);

    matmul_kernel<<<dim3(7, 7, Bc), dim3(256), 0, stream>>>(buf, out);
}